// Round 1
// 86.016 us; speedup vs baseline: 1.2730x; 1.2730x over previous
//
#include <hip/hip_runtime.h>
#include <hip/hip_bf16.h>
#include <math.h>

#define N 4096

// Occupancy round: previous version ran every kernel at 256x256 = 1 block/CU
// = 1 wave/SIMD (zero TLP; exp/LDS/f64 latency fully exposed).
// k_A/k_B/k_reduce/k_finish2 are VGPR-light -> 1024-thread blocks (4 waves/SIMD).
// k_C is VGPR-heavy (f64 cumsum + per-row suffix-min state) -> 512 threads,
// 8 cols/thread, __launch_bounds__(512,2) caps VGPR at 256 (no spill) and gives
// 2 waves/SIMD.

// K_A: fused ascending-rank + softmax matvec -> y, single pass.
// 16 waves/block, wave w owns element i0 = 16b + w. Row max of logits is 0
// (diagonal), so single-pass exp == jax's subtract-max softmax exactly.
__global__ __launch_bounds__(1024, 4)
void k_A(const float* __restrict__ preds, const float* __restrict__ target,
         float* __restrict__ y) {
    __shared__ __align__(16) float4 sp4[N / 4];
    __shared__ __align__(16) float4 st4[N / 4];
    int tid = threadIdx.x;
    int b = blockIdx.x;
    int lane = tid & 63, wid = tid >> 6;
    const float4* gp = (const float4*)preds;
    const float4* gt = (const float4*)target;
    sp4[tid] = gp[tid];
    st4[tid] = gt[tid];
    __syncthreads();
    const float* sp = (const float*)sp4;
    int i0 = b * 16 + wid;
    float xv = sp[i0];
    float Z = 0.f, Nm = 0.f;
    int cnt = 0;
    #pragma unroll 4
    for (int m = 0; m < 16; m++) {
        int q = lane + 64 * m;          // float4 index; conflict-free b128
        float4 p4 = sp4[q];
        float4 t4 = st4[q];
        int j = q * 4;
        float d0 = xv - p4.x, d1 = xv - p4.y, d2 = xv - p4.z, d3 = xv - p4.w;
        float e0 = __expf(-100.0f * d0 * d0);
        float e1 = __expf(-100.0f * d1 * d1);
        float e2 = __expf(-100.0f * d2 * d2);
        float e3 = __expf(-100.0f * d3 * d3);
        Z += (e0 + e1) + (e2 + e3);
        Nm += e0 * t4.x + e1 * t4.y + e2 * t4.z + e3 * t4.w;
        cnt += (p4.x < xv) || (p4.x == xv && (j + 0) < i0);
        cnt += (p4.y < xv) || (p4.y == xv && (j + 1) < i0);
        cnt += (p4.z < xv) || (p4.z == xv && (j + 2) < i0);
        cnt += (p4.w < xv) || (p4.w == xv && (j + 3) < i0);
    }
    #pragma unroll
    for (int d = 32; d; d >>= 1) {
        Z += __shfl_down(Z, d);
        Nm += __shfl_down(Nm, d);
        cnt += __shfl_down(cnt, d);
    }
    if (lane == 0) y[cnt] = Nm / Z;
}

// K_B: descending stable rank of y; s[r] = y*100, perm[r] = i.
// 1024 thr: 64 slices x 16 float4 each.
__global__ __launch_bounds__(1024, 4)
void k_B(const float* __restrict__ y, float* __restrict__ s_out,
         int* __restrict__ perm_out) {
    __shared__ __align__(16) float sy[N];
    __shared__ int part[16][65];
    int tid = threadIdx.x;
    int b = blockIdx.x;
    ((float4*)sy)[tid] = ((const float4*)y)[tid];
    __syncthreads();
    int eloc = tid & 15;
    int slice = tid >> 4;               // 0..63
    int i = b * 16 + eloc;
    float v = sy[i];
    int cnt = 0;
    const float4* sy4 = (const float4*)sy;
    #pragma unroll
    for (int it = 0; it < 16; it++) {
        int q = slice * 16 + ((it + slice) & 15);
        float4 a = sy4[q];
        int j = q * 4;
        cnt += (a.x > v) || (a.x == v && (j + 0) < i);
        cnt += (a.y > v) || (a.y == v && (j + 1) < i);
        cnt += (a.z > v) || (a.z == v && (j + 2) < i);
        cnt += (a.w > v) || (a.w == v && (j + 3) < i);
    }
    part[eloc][slice] = cnt;
    __syncthreads();
    if (tid < 16) {
        int r = 0;
        #pragma unroll
        for (int q = 0; q < 64; q++) r += part[tid][q];
        int i2 = b * 16 + tid;
        s_out[r] = sy[i2] * 100.0f;
        perm_out[r] = i2;
    }
}

// K_C: fused f64 cumsum of z[t]=(N-t)-s[t] + isotonic min-max scan.
// 512 threads, 8 columns/thread. Block b covers rows j in [16b,16b+16);
// writes per-block column-max P[b][i] only for i >= 16b.
__global__ __launch_bounds__(512, 2)
void k_C(const float* __restrict__ s, float* __restrict__ P) {
    __shared__ __align__(16) float mArr[4][512];
    __shared__ float incl[4][513];
    __shared__ double cj[16];
    __shared__ double wsum[8];
    int tid = threadIdx.x;
    int b = blockIdx.x;
    int j0 = b * 16;
    int kbase = tid * 8;
    int lane = tid & 63, wid = tid >> 6;
    double loc[8];
    {
        const float4* s4 = (const float4*)s;
        double tot = 0.0;
        #pragma unroll
        for (int q = 0; q < 2; q++) {
            float4 a = s4[tid * 2 + q];
            int t0 = kbase + q * 4;
            tot += (double)(N - (t0 + 0)) - (double)a.x; loc[q * 4 + 0] = tot;
            tot += (double)(N - (t0 + 1)) - (double)a.y; loc[q * 4 + 1] = tot;
            tot += (double)(N - (t0 + 2)) - (double)a.z; loc[q * 4 + 2] = tot;
            tot += (double)(N - (t0 + 3)) - (double)a.w; loc[q * 4 + 3] = tot;
        }
        double w = tot;
        #pragma unroll
        for (int d = 1; d < 64; d <<= 1) {
            double o = __shfl_up(w, d);
            if (lane >= d) w += o;
        }
        if (lane == 63) wsum[wid] = w;
        __syncthreads();
        double base = 0.0;
        #pragma unroll
        for (int q = 0; q < 8; q++) if (q < wid) base += wsum[q];
        double excl = base + (w - tot);
        #pragma unroll
        for (int e = 0; e < 8; e++) loc[e] += excl; // loc[e] = cs[kbase+1+e]
        if (tid == 2 * b) {                          // owns cs[16b..16b+8)
            cj[0] = excl;
            #pragma unroll
            for (int m = 1; m < 8; m++) cj[m] = loc[m - 1];
        }
        if (tid == 2 * b + 1) {                      // owns cs[16b+8..16b+16)
            cj[8] = excl;
            #pragma unroll
            for (int m = 1; m < 8; m++) cj[8 + m] = loc[m - 1];
        }
    }
    __syncthreads();
    float vloc[8];
    #pragma unroll
    for (int e = 0; e < 8; e++) vloc[e] = -INFINITY;
    float ls[4][8];
    // Threads with every column < j0 can only ever contribute INF.
    bool live = (tid >= 2 * b);
    for (int grp = 0; grp < 4; grp++) {
        if (live) {
            #pragma unroll
            for (int rq = 0; rq < 4; rq++) {
                int j = j0 + grp * 4 + rq;
                double csj = cj[grp * 4 + rq];
                float run = INFINITY;
                #pragma unroll
                for (int e = 7; e >= 0; e--) {
                    int k = kbase + e;
                    float f = INFINITY;
                    if (k >= j) f = (float)(loc[e] - csj) * __builtin_amdgcn_rcpf((float)(k - j + 1));
                    run = fminf(f, run);
                    ls[rq][e] = run;
                }
                mArr[rq][tid] = run;
            }
        } else {
            #pragma unroll
            for (int rq = 0; rq < 4; rq++) mArr[rq][tid] = INFINITY;
        }
        __syncthreads();
        // Suffix-min scan over the 512 per-thread chunk minima; wave w handles
        // row-group member w, 8 chunks per lane.
        if (wid < 4) {
            const float4* mv = (const float4*)mArr[wid];
            float4 x0 = mv[2 * lane + 0];
            float4 x1 = mv[2 * lane + 1];
            float s7 = x1.w;
            float s6 = fminf(x1.z, s7);
            float s5 = fminf(x1.y, s6);
            float s4 = fminf(x1.x, s5);
            float s3 = fminf(x0.w, s4);
            float s2 = fminf(x0.z, s3);
            float s1 = fminf(x0.y, s2);
            float s0 = fminf(x0.x, s1);
            float t = s0;
            #pragma unroll
            for (int d = 1; d < 64; d <<= 1) {
                float o = __shfl_down(t, d);
                if (lane + d < 64) t = fminf(t, o);
            }
            float after = __shfl_down(t, 1);
            if (lane == 63) after = INFINITY;
            incl[wid][8 * lane + 0] = fminf(s0, after);
            incl[wid][8 * lane + 1] = fminf(s1, after);
            incl[wid][8 * lane + 2] = fminf(s2, after);
            incl[wid][8 * lane + 3] = fminf(s3, after);
            incl[wid][8 * lane + 4] = fminf(s4, after);
            incl[wid][8 * lane + 5] = fminf(s5, after);
            incl[wid][8 * lane + 6] = fminf(s6, after);
            incl[wid][8 * lane + 7] = fminf(s7, after);
            if (lane == 0) incl[wid][512] = INFINITY;
        }
        __syncthreads();
        if (live) {
            #pragma unroll
            for (int rq = 0; rq < 4; rq++) {
                int j = j0 + grp * 4 + rq;
                float aft = incl[rq][tid + 1];
                #pragma unroll
                for (int e = 0; e < 8; e++) {
                    int i = kbase + e;
                    float sv = fminf(ls[rq][e], aft);
                    if (i >= j) vloc[e] = fmaxf(vloc[e], sv);
                }
            }
        }
        __syncthreads();
    }
    if (tid >= 2 * b) {   // columns [8tid, 8tid+8) valid iff >= j0
        float4* P4 = (float4*)(P + (size_t)b * N);
        P4[tid * 2 + 0] = make_float4(vloc[0], vloc[1], vloc[2], vloc[3]);
        P4[tid * 2 + 1] = make_float4(vloc[4], vloc[5], vloc[6], vloc[7]);
    }
}

// K_reduce: T[i] = max_{b<=blk} P[b][i]; r[perm[i]] = s[i] + T[i].
// 1024 thr: 64 slices x 4 source blocks each.
__global__ __launch_bounds__(1024, 4)
void k_reduce(const float* __restrict__ P, const float* __restrict__ s,
              const int* __restrict__ perm, float* __restrict__ r) {
    __shared__ float part[16][65];
    int tid = threadIdx.x;
    int col = tid & 15;
    int slice = tid >> 4;               // 0..63
    int blk = blockIdx.x;
    int i = blk * 16 + col;
    float m = -INFINITY;
    #pragma unroll
    for (int q = 0; q < 4; q++) {
        int bb = slice * 4 + q;
        if (bb <= blk) m = fmaxf(m, P[(size_t)bb * N + i]);
    }
    part[col][slice] = m;
    __syncthreads();
    if (tid < 16) {
        float T = -INFINITY;
        #pragma unroll
        for (int q = 0; q < 64; q++) T = fmaxf(T, part[tid][q]);
        int i2 = blk * 16 + tid;
        r[perm[i2]] = s[i2] + T;
    }
}

// K_finish2: diff-sum over r in original order; emit out. 1 block x 1024.
__global__ __launch_bounds__(1024, 4)
void k_finish2(const float* __restrict__ r, float* __restrict__ out) {
    __shared__ double red[16];
    int tid = threadIdx.x;
    const float4* r4 = (const float4*)r;
    float4 x = r4[tid];
    float extra = (tid < 1023) ? r[tid * 4 + 4] : 0.0f;
    double acc = 0.0;
    acc += fabs((double)x.y - (double)x.x);
    acc += fabs((double)x.z - (double)x.y);
    acc += fabs((double)x.w - (double)x.z);
    if (tid < 1023) acc += fabs((double)extra - (double)x.w);
    #pragma unroll
    for (int dd = 32; dd; dd >>= 1) acc += __shfl_down(acc, dd);
    if ((tid & 63) == 0) red[tid >> 6] = acc;
    __syncthreads();
    if (tid == 0) {
        double ds = 0.0;
        #pragma unroll
        for (int q = 0; q < 16; q++) ds += red[q];
        double xi = 1.0 - 3.0 * ds / ((double)N * (double)N - 1.0);
        out[0] = (float)(-1.0 * xi);  // loss = -WEIGHT * xi
        out[1] = (float)xi;
    }
}

extern "C" void kernel_launch(void* const* d_in, const int* in_sizes, int n_in,
                              void* d_out, int out_size, void* d_ws, size_t ws_size,
                              hipStream_t stream) {
    const float* preds  = (const float*)d_in[0];
    const float* target = (const float*)d_in[1];
    float* out = (float*)d_out;

    char* ws = (char*)d_ws;
    float* y    = (float*)(ws);            // 16 KB
    float* s    = (float*)(ws + 16384);    // 16 KB
    int*   perm = (int*)(ws + 32768);      // 16 KB
    float* r    = (float*)(ws + 49152);    // 16 KB
    float* P    = (float*)(ws + 81920);    // 4 MB

    k_A<<<256, 1024, 0, stream>>>(preds, target, y);
    k_B<<<256, 1024, 0, stream>>>(y, s, perm);
    k_C<<<256, 512, 0, stream>>>(s, P);
    k_reduce<<<256, 1024, 0, stream>>>(P, s, perm, r);
    k_finish2<<<1, 1024, 0, stream>>>(r, out);
}